// Round 6
// baseline (127.354 us; speedup 1.0000x reference)
//
#include <hip/hip_runtime.h>

// Problem constants (B, NBC, H, W, HID, OUT = 4, 128, 64, 64, 64, 1)
// ALL input tensors are float32 (reference uses jnp.float32 throughout).
#define BB   4
#define NBC  128
#define NINT 4096
#define HID  64

using half8   = __attribute__((ext_vector_type(8)))  _Float16; // MFMA f16 A/B frag (4 VGPRs)
using h2      = __attribute__((ext_vector_type(2)))  _Float16; // packed f16 pair (1 VGPR)
using float16 = __attribute__((ext_vector_type(16))) float;    // MFMA 32x32 acc
using f2      = __attribute__((ext_vector_type(2)))  float;
using int4v   = __attribute__((ext_vector_type(4)))  int;

static __device__ __forceinline__ h2 cvt_pkrtz(float a, float b) {
#if __has_builtin(__builtin_amdgcn_cvt_pkrtz)
    return __builtin_bit_cast(h2, __builtin_amdgcn_cvt_pkrtz(a, b));
#else
    h2 r;
    asm("v_cvt_pkrtz_f16_f32 %0, %1, %2" : "=v"(r) : "v"(a), "v"(b));
    return r;
#endif
}

// ---------------------------------------------------------------------------
// Kernel 1: boundary encoder + a' = relu(relu(x@W0+b0)@W1+b1) @ G0w[:64] + G0b
// f32 a' output — PRECISION-CRITICAL: a' must reach the a'+c add in f32
// (f16 a' caused 1.05e-2 absmax via cancellation at relu boundaries, r1/r2).
// ---------------------------------------------------------------------------
__global__ void __launch_bounds__(256) bge_prep(
    const float* __restrict__ binfo,  // (4,128,3)
    const float* __restrict__ W0,     // (3,64)
    const float* __restrict__ b0,     // (64)
    const float* __restrict__ W1,     // (64,64)
    const float* __restrict__ b1,     // (64)
    const float* __restrict__ G0w,    // (66,64)
    const float* __restrict__ G0b,    // (64)
    float* __restrict__ aprime)       // (4,128,64) fp32
{
    __shared__ float sW1[HID * HID];   // 16 KB
    __shared__ float sG0[HID * HID];   // 16 KB
    __shared__ float shv [4][HID];
    __shared__ float shv2[4][HID];

    const int tid = threadIdx.x;
    const int wv  = tid >> 6;
    const int t   = tid & 63;
    const int row = blockIdx.x * 4 + wv;

    for (int idx = tid; idx < HID * HID / 4; idx += 256) {
        ((float4*)sW1)[idx] = ((const float4*)W1)[idx];
        ((float4*)sG0)[idx] = ((const float4*)G0w)[idx];
    }

    const float x0 = binfo[row*3+0];
    const float x1 = binfo[row*3+1];
    const float x2 = binfo[row*3+2];
    float h = fmaxf(x0*W0[t] + x1*W0[64+t] + x2*W0[128+t] + b0[t], 0.0f);
    shv[wv][t] = h;
    __syncthreads();                       // covers sW1/sG0 staging + shv

    float acc = b1[t];
    #pragma unroll 8
    for (int k = 0; k < HID; ++k) acc += shv[wv][k] * sW1[k*64 + t];
    shv2[wv][t] = fmaxf(acc, 0.0f);
    __syncthreads();

    float a = G0b[t];
    #pragma unroll 8
    for (int k = 0; k < HID; ++k) a += shv2[wv][k] * sG0[k*64 + t];
    aprime[row*HID + t] = a;
}

// ---------------------------------------------------------------------------
// Kernel 2: fused h1 build -> MFMA f16 -> relu+dot2 -> partial mean(bc)
// Round-6 change: TLP RESTRUCTURE (R0-R5 all stuck ~40-43 µs with VALUBusy
// 38-46%, MfmaUtil 15%, Occupancy 18.5% = 16 waves/CU — latency-bound,
// intra-wave ILP attempts flat). bc-reduction split 2-way:
//   grid (NINT/32, BB*2): blockIdx.y = b*2 + bch; block stages 64 a' rows
//   (16 KB), wave wv handles bc in [bch*64 + wv*8, +8). 1024 blocks
//   -> 24 waves/CU resident (VGPR-capped 6/SIMD) + queued spillover.
// Partials combined via one atomicAdd per output per block (2 per address);
// out zeroed by hipMemsetAsync on the stream before launch. Each block adds
// tot/128 + G2b/2. Final reduction per wave via __shfl_xor butterfly over
// the 32-lane halves (masks 1..16 stay in-half) — no big LDS scratch.
// Per-element math identical to R5 (only summation association differs).
// MFMA 32x32x16 f16: A[m=lane&31 (=i)][k=hf*8+jj(+16*st)], B same k-map,
// C/D: col=lane&31 (= n), row=(reg&3)+8*(reg>>2)+4*hf (= i).
// ---------------------------------------------------------------------------
__global__ void __launch_bounds__(512) bge_main(
    const float* __restrict__ icoord, // (4,4096,2)
    const float* __restrict__ G0w,    // (66,64)  rows 64,65 used here
    const float* __restrict__ G1w,    // (64,64)
    const float* __restrict__ G1b,    // (64)
    const float* __restrict__ G2w,    // (64,1)
    const float* __restrict__ G2b,    // (1)
    const float* __restrict__ aprime, // (4,128,64) fp32
    float* __restrict__ out)          // (4,4096), pre-zeroed, atomicAdd target
{
    // ldsA: 65 rows x 64 f32 (row 64 = overrun pad for the pipeline prologue
    // of wave 7) + red: 8 waves x 2 halves x 16 rows
    __shared__ __align__(16) float smem[65*HID + 256];   // ~17.7 KB
    float* const ldsA = smem;
    float* const red  = smem + 65*HID;

    const int b    = blockIdx.y >> 1;
    const int bch  = blockIdx.y & 1;       // bc half: rows [bch*64, bch*64+64)
    const int i0   = blockIdx.x * 32;
    const int tid  = threadIdx.x;
    const int wv   = tid >> 6;       // 0..7
    const int lane = tid & 63;
    const int hf   = lane >> 5;
    const int ln   = lane & 31;

    // stage this block's 64 a' rows into LDS, coalesced float4 (2 iters)
    {
        const float4* src = (const float4*)(aprime + ((size_t)b * NBC + bch*64) * HID);
        float4* dst = (float4*)ldsA;
        for (int idx = tid; idx < 64*HID/4; idx += 512) dst[idx] = src[idx];
    }

    // per-lane c contribution as f2 pairs: cre2[st][j] covers k = st*16+hf*8+2j, +1
    const int i = i0 + ln;
    const float cx = icoord[((size_t)b*NINT + i)*2 + 0];
    const float cy = icoord[((size_t)b*NINT + i)*2 + 1];
    f2 cre2[4][4];
    #pragma unroll
    for (int st = 0; st < 4; ++st)
        #pragma unroll
        for (int j = 0; j < 4; ++j) {
            const int k = st*16 + hf*8 + 2*j;
            f2 t;
            t[0] = cx*G0w[64*64 + k]     + cy*G0w[65*64 + k];
            t[1] = cx*G0w[64*64 + k + 1] + cy*G0w[65*64 + k + 1];
            cre2[st][j] = t;
        }

    // B fragments of G1w (fp32 -> f16 RNE, once): k = st*16+hf*8+jj, n = t*32+ln
    half8 bfrag[4][2];
    #pragma unroll
    for (int st = 0; st < 4; ++st)
        #pragma unroll
        for (int t = 0; t < 2; ++t)
            #pragma unroll
            for (int jj = 0; jj < 8; ++jj) {
                const int k = st*16 + hf*8 + jj;
                bfrag[st][t][jj] = (_Float16)(G1w[k*64 + t*32 + ln]);
            }

    const float b1v0 = G1b[ln],  b1v1 = G1b[32 + ln];
    const float g2v0 = G2w[ln],  g2v1 = G2w[32 + ln];
    const float g2bv = G2b[0];

    // bias pair spanning the two n-halves (matches (acc0[r], acc1[r]) pairing)
    f2 bb; bb[0] = b1v0; bb[1] = b1v1;
    // packed g2 pair covering the two n-halves of this lane
    h2 g2pk; g2pk[0] = (_Float16)g2v0; g2pk[1] = (_Float16)g2v1;

    h2 z2; z2[0] = (_Float16)0.0f; z2[1] = (_Float16)0.0f;
    const float16 zc = (float16)0.0f;     // C operand for st==0
    float s[16];
    #pragma unroll
    for (int r = 0; r < 16; ++r) s[r] = 0.0f;

    __syncthreads();  // ldsA ready

    const int bc0 = wv * 8;   // row within the staged 64-row slab

    // ---- A-fragment build for row `arow` (f32 add MUST stay f32) ----
    #define BUILD_AFS(DST, AROW)                                               \
        {                                                                      \
            const float* arow_ = (AROW);                                       \
            _Pragma("unroll")                                                  \
            for (int st = 0; st < 4; ++st) {                                   \
                const float4* ap4 = (const float4*)(arow_ + st*16 + hf*8);     \
                const float4 v0 = ap4[0], v1 = ap4[1];                         \
                f2 p0, p1, p2, p3;                                             \
                p0[0] = v0.x; p0[1] = v0.y;                                    \
                p1[0] = v0.z; p1[1] = v0.w;                                    \
                p2[0] = v1.x; p2[1] = v1.y;                                    \
                p3[0] = v1.z; p3[1] = v1.w;                                    \
                p0 += cre2[st][0];                                             \
                p1 += cre2[st][1];                                             \
                p2 += cre2[st][2];                                             \
                p3 += cre2[st][3];                                             \
                h2 c0 = cvt_pkrtz(p0[0], p0[1]);                               \
                h2 c1 = cvt_pkrtz(p1[0], p1[1]);                               \
                h2 c2 = cvt_pkrtz(p2[0], p2[1]);                               \
                h2 c3 = cvt_pkrtz(p3[0], p3[1]);                               \
                c0 = __builtin_elementwise_max(c0, z2);                        \
                c1 = __builtin_elementwise_max(c1, z2);                        \
                c2 = __builtin_elementwise_max(c2, z2);                        \
                c3 = __builtin_elementwise_max(c3, z2);                        \
                int4v di;                                                      \
                di[0] = __builtin_bit_cast(int, c0);                           \
                di[1] = __builtin_bit_cast(int, c1);                           \
                di[2] = __builtin_bit_cast(int, c2);                           \
                di[3] = __builtin_bit_cast(int, c3);                           \
                DST[st] = __builtin_bit_cast(half8, di);                       \
            }                                                                  \
        }

    // pipeline prologue: build fragments for the first bc row
    half8 afs[4];
    BUILD_AFS(afs, ldsA + bc0*HID);

    #pragma unroll 4
    for (int j = 0; j < 8; ++j) {
        // 1) MFMA on the fragments built last iteration
        float16 acc0 = __builtin_amdgcn_mfma_f32_32x32x16_f16(afs[0], bfrag[0][0], zc, 0, 0, 0);
        float16 acc1 = __builtin_amdgcn_mfma_f32_32x32x16_f16(afs[0], bfrag[0][1], zc, 0, 0, 0);
        acc0 = __builtin_amdgcn_mfma_f32_32x32x16_f16(afs[1], bfrag[1][0], acc0, 0, 0, 0);
        acc1 = __builtin_amdgcn_mfma_f32_32x32x16_f16(afs[1], bfrag[1][1], acc1, 0, 0, 0);
        acc0 = __builtin_amdgcn_mfma_f32_32x32x16_f16(afs[2], bfrag[2][0], acc0, 0, 0, 0);
        acc1 = __builtin_amdgcn_mfma_f32_32x32x16_f16(afs[2], bfrag[2][1], acc1, 0, 0, 0);
        acc0 = __builtin_amdgcn_mfma_f32_32x32x16_f16(afs[3], bfrag[3][0], acc0, 0, 0, 0);
        acc1 = __builtin_amdgcn_mfma_f32_32x32x16_f16(afs[3], bfrag[3][1], acc1, 0, 0, 0);

        // 2) build next row's fragments (independent — fills the MFMA shadow;
        //    j==7 reads row bc0+8 (row 64 for wv=7): in-bounds pad, unused)
        half8 afn[4];
        BUILD_AFS(afn, ldsA + (bc0 + j + 1)*HID);

        // 3) epilogue: s[r] += relu((h2+b1)) . g2 over the two n-halves
        #pragma unroll
        for (int r = 0; r < 16; ++r) {
            f2 y; y[0] = acc0[r]; y[1] = acc1[r];
            y += bb;                              // f32 bias add
            h2 hp = cvt_pkrtz(y[0], y[1]);        // -> f16 (rtz)
            hp = __builtin_elementwise_max(hp, z2);   // relu in f16
#if __has_builtin(__builtin_amdgcn_fdot2)
            s[r] = __builtin_amdgcn_fdot2(hp, g2pk, s[r], false);  // v_dot2_f32_f16
#else
            s[r] += (float)hp[0]*(float)g2pk[0] + (float)hp[1]*(float)g2pk[1];
#endif
        }

        // 4) rotate
        afs[0] = afn[0]; afs[1] = afn[1]; afs[2] = afn[2]; afs[3] = afn[3];
    }
    #undef BUILD_AFS

    // wave-level reduce: sum s[r] over the 32 lanes of each half
    // (xor masks 1..16 stay within the 32-lane half = the reduction domain)
    #pragma unroll
    for (int r = 0; r < 16; ++r) {
        float v = s[r];
        v += __shfl_xor(v, 1);
        v += __shfl_xor(v, 2);
        v += __shfl_xor(v, 4);
        v += __shfl_xor(v, 8);
        v += __shfl_xor(v, 16);
        s[r] = v;
    }
    if (ln == 0) {
        #pragma unroll
        for (int r = 0; r < 16; ++r) red[wv*32 + hf*16 + r] = s[r];
    }
    __syncthreads();

    // 32 threads: combine the 8 waves' partials for each output row m,
    // then one atomicAdd per output (2 blocks contribute per address)
    if (tid < 32) {
        const int m   = tid;                       // interior row in tile
        const int h_m = (m >> 2) & 1;
        const int r_m = (m & 3) | ((m >> 3) << 2);
        float acc = 0.0f;
        #pragma unroll
        for (int w = 0; w < 8; ++w) acc += red[w*32 + h_m*16 + r_m];
        atomicAdd(out + (size_t)b*NINT + i0 + m, acc * (1.0f/128.0f) + g2bv * 0.5f);
    }
}

// ---------------------------------------------------------------------------
extern "C" void kernel_launch(void* const* d_in, const int* in_sizes, int n_in,
                              void* d_out, int out_size, void* d_ws, size_t ws_size,
                              hipStream_t stream) {
    const float* binfo  = (const float*)d_in[0];
    const float* icoord = (const float*)d_in[1];
    const float* W0     = (const float*)d_in[2];
    const float* b0     = (const float*)d_in[3];
    const float* W1     = (const float*)d_in[4];
    const float* b1     = (const float*)d_in[5];
    const float* G0w    = (const float*)d_in[6];
    const float* G0b    = (const float*)d_in[7];
    const float* G1w    = (const float*)d_in[8];
    const float* G1b    = (const float*)d_in[9];
    const float* G2w    = (const float*)d_in[10];
    const float* G2b    = (const float*)d_in[11];

    float* aprime = (float*)d_ws;   // 4*128*64 fp32 = 128 KB scratch

    // out is an atomicAdd target: zero it first (stream-ordered, capture-legal)
    hipMemsetAsync(d_out, 0, (size_t)BB * NINT * sizeof(float), stream);

    hipLaunchKernelGGL(bge_prep, dim3(BB*NBC/4), dim3(256), 0, stream,
                       binfo, W0, b0, W1, b1, G0w, G0b, aprime);
    hipLaunchKernelGGL(bge_main, dim3(NINT/32, BB*2), dim3(512), 0, stream,
                       icoord, G0w, G1w, G1b, G2w, G2b, aprime,
                       (float*)d_out);
}

// Round 7
// 113.034 us; speedup vs baseline: 1.1267x; 1.1267x over previous
//
#include <hip/hip_runtime.h>

// Problem constants (B, NBC, H, W, HID, OUT = 4, 128, 64, 64, 64, 1)
// ALL input tensors are float32 (reference uses jnp.float32 throughout).
#define BB   4
#define NBC  128
#define NINT 4096
#define HID  64

using half8   = __attribute__((ext_vector_type(8)))  _Float16; // MFMA f16 A/B frag (4 VGPRs)
using h2      = __attribute__((ext_vector_type(2)))  _Float16; // packed f16 pair (1 VGPR)
using float16 = __attribute__((ext_vector_type(16))) float;    // MFMA 32x32 acc
using f2      = __attribute__((ext_vector_type(2)))  float;
using int4v   = __attribute__((ext_vector_type(4)))  int;

static __device__ __forceinline__ h2 cvt_pkrtz(float a, float b) {
#if __has_builtin(__builtin_amdgcn_cvt_pkrtz)
    return __builtin_bit_cast(h2, __builtin_amdgcn_cvt_pkrtz(a, b));
#else
    h2 r;
    asm("v_cvt_pkrtz_f16_f32 %0, %1, %2" : "=v"(r) : "v"(a), "v"(b));
    return r;
#endif
}

// ---------------------------------------------------------------------------
// Kernel 1: boundary encoder + a' = relu(relu(x@W0+b0)@W1+b1) @ G0w[:64] + G0b
// f32 a' output — PRECISION-CRITICAL: a' must reach the a'+c add in f32
// (f16 a' caused 1.05e-2 absmax via cancellation at relu boundaries, r1/r2).
// ---------------------------------------------------------------------------
__global__ void __launch_bounds__(256) bge_prep(
    const float* __restrict__ binfo,  // (4,128,3)
    const float* __restrict__ W0,     // (3,64)
    const float* __restrict__ b0,     // (64)
    const float* __restrict__ W1,     // (64,64)
    const float* __restrict__ b1,     // (64)
    const float* __restrict__ G0w,    // (66,64)
    const float* __restrict__ G0b,    // (64)
    float* __restrict__ aprime)       // (4,128,64) fp32
{
    __shared__ float sW1[HID * HID];   // 16 KB
    __shared__ float sG0[HID * HID];   // 16 KB
    __shared__ float shv [4][HID];
    __shared__ float shv2[4][HID];

    const int tid = threadIdx.x;
    const int wv  = tid >> 6;
    const int t   = tid & 63;
    const int row = blockIdx.x * 4 + wv;

    for (int idx = tid; idx < HID * HID / 4; idx += 256) {
        ((float4*)sW1)[idx] = ((const float4*)W1)[idx];
        ((float4*)sG0)[idx] = ((const float4*)G0w)[idx];
    }

    const float x0 = binfo[row*3+0];
    const float x1 = binfo[row*3+1];
    const float x2 = binfo[row*3+2];
    float h = fmaxf(x0*W0[t] + x1*W0[64+t] + x2*W0[128+t] + b0[t], 0.0f);
    shv[wv][t] = h;
    __syncthreads();                       // covers sW1/sG0 staging + shv

    float acc = b1[t];
    #pragma unroll 8
    for (int k = 0; k < HID; ++k) acc += shv[wv][k] * sW1[k*64 + t];
    shv2[wv][t] = fmaxf(acc, 0.0f);
    __syncthreads();

    float a = G0b[t];
    #pragma unroll 8
    for (int k = 0; k < HID; ++k) a += shv2[wv][k] * sG0[k*64 + t];
    aprime[row*HID + t] = a;
}

// ---------------------------------------------------------------------------
// Kernel 2: fused h1 build -> MFMA f16 (bias in C) -> relu+dot2 -> mean(bc)
// grid (128, 4): blockIdx.x = interior tile of 32, blockIdx.y = batch.
// 512 threads = 8 waves; wave w handles bc in [16w, 16w+16).
//
// Round-7: REVERT to the R4 structure (best measured: no explicit pipeline —
// the R5 rotation added pair-assembly movs and regressed; the R6 2-way bc
// split duplicated per-wave setup with no occupancy gain and regressed).
// Two surgical changes on top of R4:
//  * Tail reduction via __shfl_xor butterfly (masks 1..16 stay inside each
//    32-lane half = the reduction domain). Removes the stride-17 ldsS scratch
//    entirely -> SQ_LDS_BANK_CONFLICT 930K -> ~0, LDS 36.9 -> 33 KB.
//  * s_setprio(1) around the MFMA pairs (T5: waves here are barrier-free and
//    naturally phase-desynced — the regime where setprio helps).
// A-path (PRECISION: a'+c add MUST stay f32): f32 a' in LDS, v_pk_add_f32,
// cvt_pkrtz (unpaired srcs), v_pk_max_f16 relu, f16 MFMA.
// MFMA 32x32x16 f16: A[m=lane&31 (=i)][k=hf*8+jj(+16*st)], B same k-map,
// C/D: col=lane&31 (= n), row=(reg&3)+8*(reg>>2)+4*hf (= i).
// ---------------------------------------------------------------------------
__global__ void __launch_bounds__(512) bge_main(
    const float* __restrict__ icoord, // (4,4096,2)
    const float* __restrict__ G0w,    // (66,64)  rows 64,65 used here
    const float* __restrict__ G1w,    // (64,64)
    const float* __restrict__ G1b,    // (64)
    const float* __restrict__ G2w,    // (64,1)
    const float* __restrict__ G2b,    // (1)
    const float* __restrict__ aprime, // (4,128,64) fp32
    float* __restrict__ out)          // (4,4096)
{
    // ldsA: 128 rows x 64 f32 (32 KB) + red: 8 waves x 2 halves x 16 rows
    __shared__ __align__(16) float smem[NBC*HID + 256];   // 33 KB
    float* const ldsA = smem;
    float* const red  = smem + NBC*HID;

    const int b    = blockIdx.y;
    const int i0   = blockIdx.x * 32;
    const int tid  = threadIdx.x;
    const int wv   = tid >> 6;       // 0..7
    const int lane = tid & 63;
    const int hf   = lane >> 5;
    const int ln   = lane & 31;

    // stage a' (this batch, all 128 bc rows) into LDS, coalesced float4
    {
        const float4* src = (const float4*)(aprime + (size_t)b * NBC * HID);
        float4* dst = (float4*)ldsA;
        for (int idx = tid; idx < NBC*HID/4; idx += 512) dst[idx] = src[idx];
    }

    // per-lane c contribution as f2 pairs: cre2[st][j] covers k = st*16+hf*8+2j, +1
    const int i = i0 + ln;
    const float cx = icoord[((size_t)b*NINT + i)*2 + 0];
    const float cy = icoord[((size_t)b*NINT + i)*2 + 1];
    f2 cre2[4][4];
    #pragma unroll
    for (int st = 0; st < 4; ++st)
        #pragma unroll
        for (int j = 0; j < 4; ++j) {
            const int k = st*16 + hf*8 + 2*j;
            f2 t;
            t[0] = cx*G0w[64*64 + k]     + cy*G0w[65*64 + k];
            t[1] = cx*G0w[64*64 + k + 1] + cy*G0w[65*64 + k + 1];
            cre2[st][j] = t;
        }

    // B fragments of G1w (fp32 -> f16 RNE, once): k = st*16+hf*8+jj, n = t*32+ln
    half8 bfrag[4][2];
    #pragma unroll
    for (int st = 0; st < 4; ++st)
        #pragma unroll
        for (int t = 0; t < 2; ++t)
            #pragma unroll
            for (int jj = 0; jj < 8; ++jj) {
                const int k = st*16 + hf*8 + jj;
                bfrag[st][t][jj] = (_Float16)(G1w[k*64 + t*32 + ln]);
            }

    const float b1v0 = G1b[ln],  b1v1 = G1b[32 + ln];
    const float g2v0 = G2w[ln],  g2v1 = G2w[32 + ln];
    const float g2bv = G2b[0];

    // bias-in-C: C-operand splats (n = lane -> uniform over the 16 regs)
    float16 cb0, cb1;
    #pragma unroll
    for (int r = 0; r < 16; ++r) { cb0[r] = b1v0; cb1[r] = b1v1; }

    // packed g2 pair covering the two n-halves of this lane
    h2 g2pk; g2pk[0] = (_Float16)g2v0; g2pk[1] = (_Float16)g2v1;

    h2 z2; z2[0] = (_Float16)0.0f; z2[1] = (_Float16)0.0f;
    float s[16];
    #pragma unroll
    for (int r = 0; r < 16; ++r) s[r] = 0.0f;

    __syncthreads();  // ldsA ready

    #pragma unroll 2
    for (int bc = wv*16; bc < wv*16 + 16; ++bc) {
        const float* arow = ldsA + bc*HID;
        float16 acc0, acc1;
        #pragma unroll
        for (int st = 0; st < 4; ++st) {
            const float4* ap4 = (const float4*)(arow + st*16 + hf*8); // bcast/half
            const float4 v0 = ap4[0], v1 = ap4[1];
            f2 p0, p1, p2, p3;
            p0[0] = v0.x; p0[1] = v0.y;
            p1[0] = v0.z; p1[1] = v0.w;
            p2[0] = v1.x; p2[1] = v1.y;
            p3[0] = v1.z; p3[1] = v1.w;
            p0 += cre2[st][0];            // v_pk_add_f32 (MUST stay f32)
            p1 += cre2[st][1];
            p2 += cre2[st][2];
            p3 += cre2[st][3];
            h2 c0 = cvt_pkrtz(p0[0], p0[1]);   // 2xf32 -> packed 2xf16
            h2 c1 = cvt_pkrtz(p1[0], p1[1]);
            h2 c2 = cvt_pkrtz(p2[0], p2[1]);
            h2 c3 = cvt_pkrtz(p3[0], p3[1]);
#if __has_builtin(__builtin_elementwise_max)
            c0 = __builtin_elementwise_max(c0, z2);   // v_pk_max_f16 relu
            c1 = __builtin_elementwise_max(c1, z2);
            c2 = __builtin_elementwise_max(c2, z2);
            c3 = __builtin_elementwise_max(c3, z2);
#else
            c0[0] = c0[0] > z2[0] ? c0[0] : z2[0]; c0[1] = c0[1] > z2[1] ? c0[1] : z2[1];
            c1[0] = c1[0] > z2[0] ? c1[0] : z2[0]; c1[1] = c1[1] > z2[1] ? c1[1] : z2[1];
            c2[0] = c2[0] > z2[0] ? c2[0] : z2[0]; c2[1] = c2[1] > z2[1] ? c2[1] : z2[1];
            c3[0] = c3[0] > z2[0] ? c3[0] : z2[0]; c3[1] = c3[1] > z2[1] ? c3[1] : z2[1];
#endif
            int4v di;
            di[0] = __builtin_bit_cast(int, c0);
            di[1] = __builtin_bit_cast(int, c1);
            di[2] = __builtin_bit_cast(int, c2);
            di[3] = __builtin_bit_cast(int, c3);
            const half8 af = __builtin_bit_cast(half8, di);
            __builtin_amdgcn_s_setprio(1);
            if (st == 0) {
                acc0 = __builtin_amdgcn_mfma_f32_32x32x16_f16(af, bfrag[0][0], cb0, 0, 0, 0);
                acc1 = __builtin_amdgcn_mfma_f32_32x32x16_f16(af, bfrag[0][1], cb1, 0, 0, 0);
            } else {
                acc0 = __builtin_amdgcn_mfma_f32_32x32x16_f16(af, bfrag[st][0], acc0, 0, 0, 0);
                acc1 = __builtin_amdgcn_mfma_f32_32x32x16_f16(af, bfrag[st][1], acc1, 0, 0, 0);
            }
            __builtin_amdgcn_s_setprio(0);
        }
        // epilogue: s[r] += relu((h2+b1) pair) . g2 over the two n-halves
        #pragma unroll
        for (int r = 0; r < 16; ++r) {
            h2 hp = cvt_pkrtz(acc0[r], acc1[r]);   // unpaired srcs, no movs
#if __has_builtin(__builtin_elementwise_max)
            hp = __builtin_elementwise_max(hp, z2);    // relu in f16
#else
            hp[0] = hp[0] > z2[0] ? hp[0] : z2[0]; hp[1] = hp[1] > z2[1] ? hp[1] : z2[1];
#endif
#if __has_builtin(__builtin_amdgcn_fdot2)
            s[r] = __builtin_amdgcn_fdot2(hp, g2pk, s[r], false);  // v_dot2_f32_f16
#else
            s[r] += (float)hp[0]*(float)g2pk[0] + (float)hp[1]*(float)g2pk[1];
#endif
        }
    }

    // wave-level reduce: sum s[r] over the 32 lanes of each half
    // (xor masks 1..16 stay within the 32-lane half = the reduction domain)
    #pragma unroll
    for (int r = 0; r < 16; ++r) {
        float v = s[r];
        v += __shfl_xor(v, 1);
        v += __shfl_xor(v, 2);
        v += __shfl_xor(v, 4);
        v += __shfl_xor(v, 8);
        v += __shfl_xor(v, 16);
        s[r] = v;
    }
    if (ln == 0) {
        #pragma unroll
        for (int r = 0; r < 16; ++r) red[wv*32 + hf*16 + r] = s[r];
    }
    __syncthreads();

    // 32 threads: combine the 8 waves' partials for each output row m
    // row m = (r&3) + 8*(r>>2) + 4*hf  ->  hf(m)=(m>>2)&1, r(m)=(m&3)|((m>>3)<<2)
    if (tid < 32) {
        const int m   = tid;
        const int h_m = (m >> 2) & 1;
        const int r_m = (m & 3) | ((m >> 3) << 2);
        float acc = 0.0f;
        #pragma unroll
        for (int w = 0; w < 8; ++w) acc += red[w*32 + h_m*16 + r_m];
        out[(size_t)b*NINT + i0 + m] = acc * (1.0f/128.0f) + g2bv;
    }
}

// ---------------------------------------------------------------------------
extern "C" void kernel_launch(void* const* d_in, const int* in_sizes, int n_in,
                              void* d_out, int out_size, void* d_ws, size_t ws_size,
                              hipStream_t stream) {
    const float* binfo  = (const float*)d_in[0];
    const float* icoord = (const float*)d_in[1];
    const float* W0     = (const float*)d_in[2];
    const float* b0     = (const float*)d_in[3];
    const float* W1     = (const float*)d_in[4];
    const float* b1     = (const float*)d_in[5];
    const float* G0w    = (const float*)d_in[6];
    const float* G0b    = (const float*)d_in[7];
    const float* G1w    = (const float*)d_in[8];
    const float* G1b    = (const float*)d_in[9];
    const float* G2w    = (const float*)d_in[10];
    const float* G2b    = (const float*)d_in[11];

    float* aprime = (float*)d_ws;   // 4*128*64 fp32 = 128 KB scratch

    hipLaunchKernelGGL(bge_prep, dim3(BB*NBC/4), dim3(256), 0, stream,
                       binfo, W0, b0, W1, b1, G0w, G0b, aprime);
    hipLaunchKernelGGL(bge_main, dim3(NINT/32, BB), dim3(512), 0, stream,
                       icoord, G0w, G1w, G1b, G2w, G2b, aprime,
                       (float*)d_out);
}